// Round 3
// baseline (1811.290 us; speedup 1.0000x reference)
//
#include <hip/hip_runtime.h>

#define X_DIM 64
#define Y_DIM 32
#define H_DIM 128
#define Z_DIM 45472
// z layout per sample (floats):
//   w0  [64][128]  @ 0
//   b0  [128]      @ 8192
//   w1  [128][128] @ 8320
//   b1  [128]      @ 24704
//   w2  [128][128] @ 24832
//   b2  [128]      @ 41216
//   w3  [128][32]  @ 41344
//   b3  [32]       @ 45440

__global__ __launch_bounds__(128, 4)
void mlp_hyper_kernel(const float* __restrict__ x,
                      const float* __restrict__ z,
                      float* __restrict__ out)
{
    const int s = blockIdx.x;          // sample index 0..8191
    const int t = threadIdx.x;         // 0..127

    const float* __restrict__ zb = z + (long long)s * Z_DIM;

    __shared__ float h[H_DIM];         // activations (x staged in first 64)
    __shared__ float red[4 * H_DIM];   // partial-sum reduce buffer (512 f32)

    // ---- stage x[s] (64 floats) into h[0..63], float4-coalesced ----
    if (t < 16) {
        ((float4*)h)[t] = ((const float4*)(x + (long long)s * X_DIM))[t];
    }
    __syncthreads();

    const int c = t & 31;   // column group: owns output cols [4c, 4c+4)
    const int g = t >> 5;   // row group 0..3

    // ---- Layer 0: 64x128 + b0, ReLU ----
    {
        const float* __restrict__ w = zb;            // w0
        float4 acc = {0.f, 0.f, 0.f, 0.f};
        #pragma unroll 16
        for (int r = 0; r < 16; ++r) {
            const int i = g * 16 + r;
            const float4 wv = *(const float4*)(w + i * H_DIM + 4 * c);
            const float hi = h[i];
            acc.x = fmaf(hi, wv.x, acc.x);
            acc.y = fmaf(hi, wv.y, acc.y);
            acc.z = fmaf(hi, wv.z, acc.z);
            acc.w = fmaf(hi, wv.w, acc.w);
        }
        *(float4*)(red + g * H_DIM + 4 * c) = acc;
        __syncthreads();
        float v = red[t] + red[H_DIM + t] + red[2 * H_DIM + t] + red[3 * H_DIM + t]
                + zb[8192 + t];
        v = fmaxf(v, 0.f);
        h[t] = v;                      // overwriting x-region is safe: all h reads done pre-sync
        __syncthreads();
    }

    // ---- Layers 1,2: 128x128 + bias, ReLU ----
    #pragma unroll 1
    for (int L = 0; L < 2; ++L) {
        const float* __restrict__ w = zb + 8320 + L * 16512;  // 128*128+128 stride
        float4 acc = {0.f, 0.f, 0.f, 0.f};
        #pragma unroll 16
        for (int r = 0; r < 32; ++r) {
            const int i = g * 32 + r;
            const float4 wv = *(const float4*)(w + i * H_DIM + 4 * c);
            const float hi = h[i];
            acc.x = fmaf(hi, wv.x, acc.x);
            acc.y = fmaf(hi, wv.y, acc.y);
            acc.z = fmaf(hi, wv.z, acc.z);
            acc.w = fmaf(hi, wv.w, acc.w);
        }
        *(float4*)(red + g * H_DIM + 4 * c) = acc;
        __syncthreads();
        float v = red[t] + red[H_DIM + t] + red[2 * H_DIM + t] + red[3 * H_DIM + t]
                + w[16384 + t];        // bias
        v = fmaxf(v, 0.f);
        h[t] = v;
        __syncthreads();
    }

    // ---- Layer 3: 128x32 + b3 (no ReLU) ----
    {
        const float* __restrict__ w = zb + 41344;    // w3
        const int jc  = t & 7;    // owns output cols [4*jc, 4*jc+4)
        const int g16 = t >> 3;   // row group 0..15, rows [8*g16, 8*g16+8)
        float4 acc = {0.f, 0.f, 0.f, 0.f};
        #pragma unroll 8
        for (int r = 0; r < 8; ++r) {
            const int i = g16 * 8 + r;
            const float4 wv = *(const float4*)(w + i * Y_DIM + 4 * jc);
            const float hi = h[i];
            acc.x = fmaf(hi, wv.x, acc.x);
            acc.y = fmaf(hi, wv.y, acc.y);
            acc.z = fmaf(hi, wv.z, acc.z);
            acc.w = fmaf(hi, wv.w, acc.w);
        }
        *(float4*)(red + g16 * Y_DIM + 4 * jc) = acc;
        __syncthreads();
        if (t < Y_DIM) {
            float v = zb[45440 + t];   // b3
            #pragma unroll
            for (int gg = 0; gg < 16; ++gg) v += red[gg * Y_DIM + t];
            out[(long long)s * Y_DIM + t] = v;
        }
    }
}

extern "C" void kernel_launch(void* const* d_in, const int* in_sizes, int n_in,
                              void* d_out, int out_size, void* d_ws, size_t ws_size,
                              hipStream_t stream) {
    const float* x = (const float*)d_in[0];
    const float* z = (const float*)d_in[1];
    float* out = (float*)d_out;
    const int n_samples = in_sizes[0] / X_DIM;   // S*B = 8192
    mlp_hyper_kernel<<<n_samples, 128, 0, stream>>>(x, z, out);
}